// Round 7
// baseline (526.368 us; speedup 1.0000x reference)
//
#include <hip/hip_runtime.h>
#include <math.h>

// Radial NUFFT + Pipe-Menon density compensation, MI355X (gfx950).
// bf16 MFMA (16x16x32), 2-term hi/lo split (3 products). Round 21:
// SINGLE-BARRIER chunk pipelines (T3/T4) + setprio (T5).
// (a) adj_gemm: triple-buffer needs only ONE barrier/chunk. WAR proof:
//     STAGE(ch+2) writes buf[(ch+2)%3], last read at iter ch-1; reads done
//     before lgkmcnt(0)@ch-1 < barrier(ch) < STAGE issue. Old barrier#2
//     deleted (36 barriers/block saved), stage flight = 2 full phases.
// (b) fwdq: 768 blocks x 192 thr (3 waves x 16 m) = exactly 3.0 blocks/CU
//     (r20's 576 = 2.25 -> 7.6% occupancy); 48KB double buffer, single
//     barrier (same WAR argument), counted vmcnt, stage issued right after
//     barrier -> one compute phase of DMA flight.
// (c) s_setprio(1) around MFMA clusters in both (phase-diverse waves now).

#define MTOT 36864      // N_SHOTS*N_SAMPLES == NPIX*NPIX
#define NPIX 192
#define SPLITS 128
#define GRP 64                  // split-groups: block g covers splits {g, g+64}
#define NCH 36                  // 2 splits x 18 chunks of 16 m
#define PG 64                   // privatized partial images (one per group)

typedef __attribute__((ext_vector_type(8))) short s16x8;
typedef __attribute__((ext_vector_type(4))) float f32x4;
typedef __attribute__((ext_vector_type(4))) unsigned u32x4;

__device__ __forceinline__ f32x4 mfma_bf16(u32x4 a, u32x4 b, f32x4 c) {
    return __builtin_amdgcn_mfma_f32_16x16x32_bf16(
        __builtin_bit_cast(s16x8, a), __builtin_bit_cast(s16x8, b), c, 0, 0, 0);
}

// async 16B/lane global->LDS (DMA); LDS dest = wave-uniform base + lane*16.
__device__ __forceinline__ void g2l16(const void* g, void* l) {
    __builtin_amdgcn_global_load_lds(
        (const __attribute__((address_space(1))) void*)g,
        (__attribute__((address_space(3))) void*)l, 16, 0, 0);
}

// Split (a,b) into packed bf16 pairs: hi = (bf16(a) | bf16(b)<<16), lo = residuals.
__device__ __forceinline__ void split_pk(float a, float b, unsigned &hi, unsigned &lo) {
    const unsigned ua = __float_as_uint(a), ub = __float_as_uint(b);
    const unsigned ha = (ua + 0x8000u) & 0xffff0000u;
    const unsigned hb = (ub + 0x8000u) & 0xffff0000u;
    hi = (ha >> 16) | hb;
    const float la = a - __uint_as_float(ha);
    const float lb = b - __uint_as_float(hb);
    lo = ((__float_as_uint(la) + 0x8000u) >> 16) |
         ((__float_as_uint(lb) + 0x8000u) & 0xffff0000u);
}

// k split into 12-bit hi + residual so kh*p (p integer, |p|<=96) is EXACT in fp32.
__device__ __forceinline__ void ksplit(float k, float &kh, float &kl) {
    kh = __uint_as_float(__float_as_uint(k) & 0xfffff000u);
    kl = k - kh;
}
__device__ __forceinline__ float redphase(float kh, float kl, float p) {
    float r = kh * p;
    r -= rintf(r);
    r = fmaf(kl, p, r);
    return r;                   // revolutions, |r| <= ~0.512
}
__device__ __forceinline__ unsigned rot16(unsigned v) {
    return __builtin_amdgcn_alignbit(v, v, 16);
}
__device__ __forceinline__ int swz(int c) {        // bank swizzle (r10-verified)
    return ((c ^ (c >> 2)) & 3) << 2;
}

// ---------------------------------------------------------------------------
// Precompute packed B phasor (cos, -sin) hi/lo, chunk-contiguous + swizzled:
// PS[mc][plane][c(192)][mi^swz(c)]  (r10-verified layout).
__global__ void precompP_k(const float* __restrict__ traj, const int comp,
                           unsigned* __restrict__ PS) {
    const int m = blockIdx.x * 256 + threadIdx.x;
    const int c = blockIdx.y;
    float kh, kl; ksplit(traj[2 * m + comp], kh, kl);
    const float ph = redphase(kh, kl, (float)(c - 96));
    const float co = __builtin_amdgcn_cosf(ph);
    const float si = __builtin_amdgcn_sinf(ph);
    unsigned h, l; split_pk(co, -si, h, l);
    const int mc = m >> 4, mi = (m & 15) ^ swz(c);
    PS[(size_t)mc * 6144 + c * 16 + mi]        = h;
    PS[(size_t)mc * 6144 + 3072 + c * 16 + mi] = l;
}

// E[m,x] = conj(A[m,x]) * d[m], packed bf16 hi/lo, same swizzled layout.
__global__ void ebuild_k(const float* __restrict__ traj,
                         const float* __restrict__ dr, const float* __restrict__ di,
                         unsigned* __restrict__ ES) {
    const int m = blockIdx.x * 256 + threadIdx.x;
    const int c = blockIdx.y;                        // x coordinate
    float kh, kl; ksplit(traj[2 * m], kh, kl);
    const float ph = redphase(kh, kl, (float)(c - 96));
    const float co = __builtin_amdgcn_cosf(ph);
    const float si = __builtin_amdgcn_sinf(ph);
    const float dr_ = dr[m], di_ = di[m];
    const float Er = co * dr_ - si * di_;
    const float Ei = co * di_ + si * dr_;
    unsigned h, l; split_pk(Er, Ei, h, l);
    const int mc = m >> 4, mi = (m & 15) ^ swz(c);
    ES[(size_t)mc * 6144 + c * 16 + mi]        = h;
    ES[(size_t)mc * 6144 + 3072 + c * 16 + mi] = l;
}

__global__ void winit_k(float* __restrict__ wr, float* __restrict__ wi) {
    const int m = blockIdx.x * 256 + threadIdx.x;
    wr[m] = 1.f; wi[m] = 0.f;
}

// ---------------------------------------------------------------------------
// Adjoint pure GEMM (r18 grid): outP[g][x,y] = sum_{m in splits g,g+64}.
// 576 blocks (64 groups x 9 tiles) of 4 waves; block owns a 64x64 tile of
// image g EXCLUSIVELY -> plain stores, zero atomics. Round 21 schedule per
// chunk: counted vmcnt(4) -> ONE s_barrier -> issue STAGE(ch+2) -> ds_read
// -> lgkmcnt(0) -> setprio(1) MFMAx24 setprio(0).
__global__ __launch_bounds__(256) void adj_gemm_k(
    const unsigned* __restrict__ ES, const unsigned* __restrict__ BS,
    float* __restrict__ outP)
{
    __shared__ unsigned sAB[3][4096];              // 48 KB triple buffer
    const int tid = threadIdx.x;
    const int lane = tid & 63, wid = tid >> 6;     // wid 0..3
    const int l15 = lane & 15, qd = lane >> 4;
    const int L = blockIdx.x;                      // 0..575, XCD swizzle
    const int xcd = L & 7, j = L >> 3;             // j 0..71
    const int g = xcd * (GRP / 8) + j / 9;         // split-group 0..63
    const int tile = j % 9;
    const int bx = tile % 3, by = tile / 3;
    const int wi = wid & 1, wj = wid >> 1;
    const int x0 = bx * 64 + wi * 32, y0 = by * 64 + wj * 32;
    float* outRe = outP + (size_t)g * (2 * MTOT);
    float* outIm = outRe + MTOT;

    f32x4 accRe[2][2], accIm[2][2];
    #pragma unroll
    for (int i = 0; i < 2; ++i)
        #pragma unroll
        for (int j2 = 0; j2 < 2; ++j2) {
            accRe[i][j2] = (f32x4){0.f, 0.f, 0.f, 0.f};
            accIm[i][j2] = (f32x4){0.f, 0.f, 0.f, 0.f};
        }

    // staging: chunk c of this block = split (g + 64*(c>=18)), local chunk c%18
    const size_t g18 = (size_t)g * 18;
    const int exo = bx * 1024 + tid * 4;           // E rows [bx*64..+64)
    const int byo = by * 1024 + tid * 4;           // B rows [by*64..+64)
    #define STAGE(c, buf)                                                  \
    {                                                                      \
        const size_t id_ = (g18 + (c) + (((c) >= 18) ? 1134 : 0)) * 6144; \
        const unsigned* E0_ = ES + id_;                                    \
        const unsigned* B0_ = BS + id_;                                    \
        g2l16(E0_ + exo,        &sAB[buf][tid * 4]);                       \
        g2l16(E0_ + 3072 + exo, &sAB[buf][1024 + tid * 4]);                \
        g2l16(B0_ + byo,        &sAB[buf][2048 + tid * 4]);                \
        g2l16(B0_ + 3072 + byo, &sAB[buf][3072 + tid * 4]);                \
    }

    // fragment LDS word offsets within a buffer (local coord; swz(local)==swz(global))
    int eoff[2], boff[2];
    #pragma unroll
    for (int t = 0; t < 2; ++t) {
        const int cE = wi * 32 + t * 16 + l15;     // local x coord 0..63
        eoff[t] = cE * 16 + ((qd ^ ((cE ^ (cE >> 2)) & 3)) << 2);
        const int cB = wj * 32 + t * 16 + l15;     // local y coord 0..63
        boff[t] = 2048 + cB * 16 + ((qd ^ ((cB ^ (cB >> 2)) & 3)) << 2);
    }

    STAGE(0, 0);                                   // prologue: chunks 0,1
    STAGE(1, 1);

    int rb = 0;                                    // read buffer = ch % 3
    for (int ch = 0; ch < NCH; ++ch) {
        // wait for stage(ch); keep stage(ch+1) in flight
        if (ch + 1 < NCH) {
            asm volatile("s_waitcnt vmcnt(4)" ::: "memory");
        } else {
            asm volatile("s_waitcnt vmcnt(0)" ::: "memory");
        }
        __builtin_amdgcn_s_barrier();              // buf rb ready; prev reads done
        if (ch + 2 < NCH) {                        // safe: see WAR proof above
            const int wb = (rb + 2 >= 3) ? rb - 1 : rb + 2;   // (ch+2)%3
            STAGE(ch + 2, wb);
        }

        const unsigned* sb = &sAB[rb][0];
        u32x4 Eh[2], El[2], PhA[2], PlA[2];
        #pragma unroll
        for (int t = 0; t < 2; ++t) {
            Eh[t]  = *(const u32x4*)(sb + eoff[t]);
            El[t]  = *(const u32x4*)(sb + 1024 + eoff[t]);
            PhA[t] = *(const u32x4*)(sb + boff[t]);
            PlA[t] = *(const u32x4*)(sb + 1024 + boff[t]);
        }
        asm volatile("s_waitcnt lgkmcnt(0)" ::: "memory");
        __builtin_amdgcn_sched_barrier(0);         // rule 18: pin MFMAs below
        __builtin_amdgcn_s_setprio(1);

        #pragma unroll
        for (int sj = 0; sj < 2; ++sj) {
            const u32x4 Ph = PhA[sj], Pl = PlA[sj];
            u32x4 Qh, Ql;
            #pragma unroll
            for (int r = 0; r < 4; ++r) {
                Qh[r] = rot16(Ph[r]) ^ 0x00008000u;                       // (sb, cb)
                Ql[r] = rot16(Pl[r]) ^ 0x00008000u;
            }
            #pragma unroll
            for (int si = 0; si < 2; ++si) {
                accRe[si][sj] = mfma_bf16(Eh[si], Ph, accRe[si][sj]);
                accRe[si][sj] = mfma_bf16(Eh[si], Pl, accRe[si][sj]);
                accRe[si][sj] = mfma_bf16(El[si], Ph, accRe[si][sj]);
                accIm[si][sj] = mfma_bf16(Eh[si], Qh, accIm[si][sj]);
                accIm[si][sj] = mfma_bf16(Eh[si], Ql, accIm[si][sj]);
                accIm[si][sj] = mfma_bf16(El[si], Qh, accIm[si][sj]);
            }
        }
        __builtin_amdgcn_s_setprio(0);
        rb = (rb + 1 == 3) ? 0 : rb + 1;
    }
    #undef STAGE

    // epilogue: PLAIN stores -- block exclusively owns tile (g, x0.., y0..)
    #pragma unroll
    for (int si = 0; si < 2; ++si)
        #pragma unroll
        for (int sj = 0; sj < 2; ++sj)
            #pragma unroll
            for (int rg = 0; rg < 4; ++rg) {
                const int x = x0 + si * 16 + qd * 4 + rg;   // C/D row
                const int y = y0 + sj * 16 + l15;           // C/D col
                outRe[x * NPIX + y] = accRe[si][sj][rg];
                outIm[x * NPIX + y] = accIm[si][sj][rg];
            }
}

// ---------------------------------------------------------------------------
// fwdq: q[m] = sum_x A[m,x] * (sum_y B[m,y]*g[x,y]).  Round 21: 768 blocks
// x 192 thr (3 waves x 16 m) = 3.0 blocks/CU uniform. G' layout
// plane[ch(12)][x(192)][yi(16)^swz(x)]; 48 KB double buffer; per chunk:
// vmcnt(0) -> ONE barrier -> issue STAGE(ch+1) (8 x g2l16, 24 KB) ->
// compute (phasor + 72 MFMA under setprio).
__global__ __launch_bounds__(192) void fwdq_k(
    const float* __restrict__ traj,
    const unsigned* __restrict__ Ghi, const unsigned* __restrict__ Glo,
    float* __restrict__ wre, float* __restrict__ wim,
    const int mode,
    float* __restrict__ qre, float* __restrict__ qim)
{
    __shared__ unsigned sG[2][6144];               // 48 KB double buffer
    const int tid = threadIdx.x;
    const int lane = tid & 63, wid = tid >> 6;     // wid 0..2
    const int l15 = lane & 15, q = lane >> 4;
    const int m = (blockIdx.x * 3 + wid) * 16 + l15;
    const float2 kk = *(const float2*)(traj + 2 * m);
    float kxh, kxl, kyh, kyl;
    ksplit(kk.x, kxh, kxl);
    ksplit(kk.y, kyh, kyl);

    f32x4 tre[12], tim[12];
    #pragma unroll
    for (int i = 0; i < 12; ++i) {
        tre[i] = (f32x4){0.f, 0.f, 0.f, 0.f};
        tim[i] = (f32x4){0.f, 0.f, 0.f, 0.f};
    }

    float bc, bs;
    { const float ph = redphase(kyh, kyl, (float)(q * 4 - 96));
      bc = __builtin_amdgcn_cosf(ph); bs = __builtin_amdgcn_sinf(ph); }
    const float r1c = __builtin_amdgcn_cosf(kk.y), r1s = __builtin_amdgcn_sinf(kk.y);
    float r16c, r16s;
    { float g = kk.y * 16.f; g -= rintf(g);
      r16c = __builtin_amdgcn_cosf(g); r16s = __builtin_amdgcn_sinf(g); }

    // fragment LDS word offsets (static-unrolled -> registers, rule 20)
    int goff[12];
    #pragma unroll
    for (int si = 0; si < 12; ++si) {
        const int row = si * 16 + l15;
        goff[si] = row * 16 + ((q ^ ((row ^ (row >> 2)) & 3)) << 2);
    }

    #define FSTAGE(c, buf)                                                     \
    {                                                                          \
        const int cb_ = (c) * 3072;                                            \
        _Pragma("unroll")                                                      \
        for (int v = 0; v < 4; ++v) {                                          \
            g2l16(Ghi + cb_ + v * 768 + tid * 4,                               \
                  &sG[buf][v * 768 + tid * 4]);                                \
            g2l16(Glo + cb_ + v * 768 + tid * 4,                               \
                  &sG[buf][3072 + v * 768 + tid * 4]);                         \
        }                                                                      \
    }

    FSTAGE(0, 0);

    for (int ch = 0; ch < 12; ++ch) {
        asm volatile("s_waitcnt vmcnt(0)" ::: "memory");   // stage(ch) landed
        __builtin_amdgcn_s_barrier();              // + prev reads done (WAR)
        if (ch < 11) FSTAGE(ch + 1, (ch + 1) & 1);

        u32x4 Ph, Pl, Qh, Ql;
        {
            float c = bc, s = bs;
            #pragma unroll
            for (int r = 0; r < 4; ++r) {
                unsigned h, l; split_pk(c, s, h, l);
                Ph[r] = h; Pl[r] = l;
                Qh[r] = rot16(h) ^ 0x00008000u;
                Ql[r] = rot16(l) ^ 0x00008000u;
                const float nc = c * r1c - s * r1s, ns = s * r1c + c * r1s;
                c = nc; s = ns;
            }
            const float nbc = bc * r16c - bs * r16s, nbs = bs * r16c + bc * r16s;
            bc = nbc; bs = nbs;
        }

        const unsigned* sb = &sG[ch & 1][0];
        __builtin_amdgcn_s_setprio(1);
        #pragma unroll
        for (int si = 0; si < 12; ++si) {
            const u32x4 gh = *(const u32x4*)(sb + goff[si]);
            const u32x4 gl = *(const u32x4*)(sb + 3072 + goff[si]);
            tre[si] = mfma_bf16(gh, Ph, tre[si]);
            tre[si] = mfma_bf16(gh, Pl, tre[si]);
            tre[si] = mfma_bf16(gl, Ph, tre[si]);
            tim[si] = mfma_bf16(gh, Qh, tim[si]);
            tim[si] = mfma_bf16(gh, Ql, tim[si]);
            tim[si] = mfma_bf16(gl, Qh, tim[si]);
        }
        __builtin_amdgcn_s_setprio(0);
    }
    #undef FSTAGE

    float qr = 0.f, qi = 0.f;
    {
        float g = kk.x * 16.f; g -= rintf(g);
        const float rc = __builtin_amdgcn_cosf(g), rs = __builtin_amdgcn_sinf(g);
        #pragma unroll
        for (int rg = 0; rg < 4; ++rg) {
            const float ph = redphase(kxh, kxl, (float)(q * 4 + rg - 96));
            float c = __builtin_amdgcn_cosf(ph), s = __builtin_amdgcn_sinf(ph);
            #pragma unroll
            for (int si = 0; si < 12; ++si) {
                const float tr = tre[si][rg], ti = tim[si][rg];
                qr += c * tr + s * ti;
                qi += c * ti - s * tr;
                const float nc = c * rc - s * rs, ns = s * rc + c * rs;
                c = nc; s = ns;
            }
        }
    }
    qr += __shfl_xor(qr, 16); qi += __shfl_xor(qi, 16);
    qr += __shfl_xor(qr, 32); qi += __shfl_xor(qi, 32);
    if (lane < 16) {
        if (mode == 0) {
            const float den = fmaxf(sqrtf(qr * qr + qi * qi), 1e-20f);
            wre[m] /= den; wim[m] /= den;
        } else {
            const float sc = sqrtf(wre[m] * wre[m] + wim[m] * wim[m]);
            qre[m] = qr * sc; qim[m] = qi * sc;
        }
    }
}

// ---------------------------------------------------------------------------
// presplit: pack (re,im) -> bf16 hi/lo planes in G' layout:
// plane[ch][x][yi ^ swz(x)], word index = ch*3072 + x*16 + (yi^swz(x)).
__global__ void presplit_k(const float* __restrict__ re, const float* __restrict__ im,
                           unsigned* __restrict__ Gh, unsigned* __restrict__ Gl) {
    const int e = blockIdx.x * 256 + threadIdx.x;
    unsigned h, l;
    split_pk(re[e], im[e], h, l);     // low16 = re (even K), high16 = im (odd K)
    const int x = e / NPIX, y = e % NPIX;
    const int o = (y >> 4) * 3072 + x * 16 + ((y & 15) ^ swz(x));
    Gh[o] = h; Gl[o] = l;
}

// Reduce PG partial images + presplit into G' layout (pipe path)
__global__ void presplitP_k(const float* __restrict__ outP,
                            unsigned* __restrict__ Gh, unsigned* __restrict__ Gl) {
    const int e = blockIdx.x * 256 + threadIdx.x;
    float re = 0.f, im = 0.f;
    #pragma unroll 8
    for (int g = 0; g < PG; ++g) {
        re += outP[(size_t)g * (2 * MTOT) + e];
        im += outP[(size_t)g * (2 * MTOT) + MTOT + e];
    }
    unsigned h, l;
    split_pk(re, im, h, l);
    const int x = e / NPIX, y = e % NPIX;
    const int o = (y >> 4) * 3072 + x * 16 + ((y & 15) ^ swz(x));
    Gh[o] = h; Gl[o] = l;
}

// Reduce PG partial images -> final output
__global__ void reduceOut_k(const float* __restrict__ outP, float* __restrict__ out) {
    const int e = blockIdx.x * 256 + threadIdx.x;
    float re = 0.f, im = 0.f;
    #pragma unroll 8
    for (int g = 0; g < PG; ++g) {
        re += outP[(size_t)g * (2 * MTOT) + e];
        im += outP[(size_t)g * (2 * MTOT) + MTOT + e];
    }
    out[e] = re; out[MTOT + e] = im;
}

// ---------------------------------------------------------------------------
extern "C" void kernel_launch(void* const* d_in, const int* in_sizes, int n_in,
                              void* d_out, int out_size, void* d_ws, size_t ws_size,
                              hipStream_t stream)
{
    const float* xin  = (const float*)d_in[0];   // (2,192,192)
    const float* traj = (const float*)d_in[1];   // (36864,2)
    float* out = (float*)d_out;                  // (2,192,192)

    char* pb = (char*)d_ws;
    unsigned* BS = (unsigned*)pb; pb += (size_t)2304 * 6144 * 4;   // 56.6 MB
    unsigned* ES = (unsigned*)pb; pb += (size_t)2304 * 6144 * 4;   // 56.6 MB
    float* outP = (float*)pb; pb += (size_t)PG * 2 * MTOT * 4;     // 18.9 MB
    float* wr   = (float*)pb; pb += MTOT * 4;
    float* wi   = (float*)pb; pb += MTOT * 4;
    float* dre  = (float*)pb; pb += MTOT * 4;
    float* dim_ = (float*)pb; pb += MTOT * 4;
    unsigned* Ghi = (unsigned*)pb; pb += MTOT * 4;
    unsigned* Glo = (unsigned*)pb; pb += MTOT * 4;

    precompP_k<<<dim3(MTOT / 256, NPIX), 256, 0, stream>>>(traj, 1, BS);
    winit_k<<<MTOT / 256, 256, 0, stream>>>(wr, wi);

    for (int it = 0; it < 3; ++it) {
        ebuild_k<<<dim3(MTOT / 256, NPIX), 256, 0, stream>>>(traj, wr, wi, ES);
        adj_gemm_k<<<9 * GRP, 256, 0, stream>>>(ES, BS, outP);
        presplitP_k<<<MTOT / 256, 256, 0, stream>>>(outP, Ghi, Glo);
        fwdq_k<<<768, 192, 0, stream>>>(traj, Ghi, Glo, wr, wi, 0, dre, dim_);
    }

    presplit_k<<<MTOT / 256, 256, 0, stream>>>(xin, xin + MTOT, Ghi, Glo);
    fwdq_k<<<768, 192, 0, stream>>>(traj, Ghi, Glo, wr, wi, 1, dre, dim_);
    ebuild_k<<<dim3(MTOT / 256, NPIX), 256, 0, stream>>>(traj, dre, dim_, ES);
    adj_gemm_k<<<9 * GRP, 256, 0, stream>>>(ES, BS, outP);
    reduceOut_k<<<MTOT / 256, 256, 0, stream>>>(outP, out);
}

// Round 8
// 508.995 us; speedup vs baseline: 1.0341x; 1.0341x over previous
//
#include <hip/hip_runtime.h>
#include <math.h>

// Radial NUFFT + Pipe-Menon density compensation, MI355X (gfx950).
// bf16 MFMA (16x16x32), 2-term hi/lo split (3 products). Round 22:
// adj_gemm = TLP-only: 4608 one-wave blocks, NO LDS, NO barriers, NO
// software pipeline. Each wave batch-issues its 8 fragment loads directly
// from global (16B/lane, fragment-ordered layout; r16/r17 proved numerics +
// cache absorption), sched_barrier(0), 24 MFMA. Latency hidden by 4
// waves/SIMD co-residency (launch_bounds(64,4) caps 128 VGPR so all 8 frags
// + 32 acc coexist -- r16/r17's VGPR=52/64 collapse is structurally
// impossible: there is no pipeline to collapse). PG=128 privatized images,
// plain stores (r18-proven). fwdq reverted byte-exact to round-0 form
// (best measured ~46us): 576 thr, 60KB LDS reg-staged double buffer.
// Rationale: m233 -- 2-phase LDS structures with 120cyc phases pay a fixed
// ~400-600cyc barrier+vmcnt+ds_read cost per chunk that no schedule tweak
// amortizes (7 rounds oscillated 463-686us).

#define MTOT 36864      // N_SHOTS*N_SAMPLES == NPIX*NPIX
#define NPIX 192
#define SPLITS 128
#define MPS (MTOT / SPLITS)     // 288 m per split
#define ADJ_CHUNKS (MPS / 16)   // 18 chunks of 16 m per split
#define PG 128                  // privatized partial images (one per split)

typedef __attribute__((ext_vector_type(8))) short s16x8;
typedef __attribute__((ext_vector_type(4))) float f32x4;
typedef __attribute__((ext_vector_type(4))) unsigned u32x4;

__device__ __forceinline__ f32x4 mfma_bf16(u32x4 a, u32x4 b, f32x4 c) {
    return __builtin_amdgcn_mfma_f32_16x16x32_bf16(
        __builtin_bit_cast(s16x8, a), __builtin_bit_cast(s16x8, b), c, 0, 0, 0);
}

// Split (a,b) into packed bf16 pairs: hi = (bf16(a) | bf16(b)<<16), lo = residuals.
__device__ __forceinline__ void split_pk(float a, float b, unsigned &hi, unsigned &lo) {
    const unsigned ua = __float_as_uint(a), ub = __float_as_uint(b);
    const unsigned ha = (ua + 0x8000u) & 0xffff0000u;
    const unsigned hb = (ub + 0x8000u) & 0xffff0000u;
    hi = (ha >> 16) | hb;
    const float la = a - __uint_as_float(ha);
    const float lb = b - __uint_as_float(hb);
    lo = ((__float_as_uint(la) + 0x8000u) >> 16) |
         ((__float_as_uint(lb) + 0x8000u) & 0xffff0000u);
}

// k split into 12-bit hi + residual so kh*p (p integer, |p|<=96) is EXACT in fp32.
__device__ __forceinline__ void ksplit(float k, float &kh, float &kl) {
    kh = __uint_as_float(__float_as_uint(k) & 0xfffff000u);
    kl = k - kh;
}
__device__ __forceinline__ float redphase(float kh, float kl, float p) {
    float r = kh * p;
    r -= rintf(r);
    r = fmaf(kl, p, r);
    return r;                   // revolutions, |r| <= ~0.512
}
__device__ __forceinline__ unsigned rot16(unsigned v) {
    return __builtin_amdgcn_alignbit(v, v, 16);
}

// ---------------------------------------------------------------------------
// Precompute packed B phasor (cos, -sin) hi/lo, chunk-contiguous, PLAIN layout
// (adj reads fragments directly from global): PS[mc][plane][c(192)][mi(16)].
__global__ void precompP_k(const float* __restrict__ traj, const int comp,
                           unsigned* __restrict__ PS) {
    const int m = blockIdx.x * 256 + threadIdx.x;
    const int c = blockIdx.y;
    float kh, kl; ksplit(traj[2 * m + comp], kh, kl);
    const float ph = redphase(kh, kl, (float)(c - 96));
    const float co = __builtin_amdgcn_cosf(ph);
    const float si = __builtin_amdgcn_sinf(ph);
    unsigned h, l; split_pk(co, -si, h, l);
    const int mc = m >> 4, mi = m & 15;
    PS[(size_t)mc * 6144 + c * 16 + mi]        = h;
    PS[(size_t)mc * 6144 + 3072 + c * 16 + mi] = l;
}

// E[m,x] = conj(A[m,x]) * d[m], packed bf16 hi/lo, same plain layout.
__global__ void ebuild_k(const float* __restrict__ traj,
                         const float* __restrict__ dr, const float* __restrict__ di,
                         unsigned* __restrict__ ES) {
    const int m = blockIdx.x * 256 + threadIdx.x;
    const int c = blockIdx.y;                        // x coordinate
    float kh, kl; ksplit(traj[2 * m], kh, kl);
    const float ph = redphase(kh, kl, (float)(c - 96));
    const float co = __builtin_amdgcn_cosf(ph);
    const float si = __builtin_amdgcn_sinf(ph);
    const float dr_ = dr[m], di_ = di[m];
    const float Er = co * dr_ - si * di_;
    const float Ei = co * di_ + si * dr_;
    unsigned h, l; split_pk(Er, Ei, h, l);
    const int mc = m >> 4, mi = m & 15;
    ES[(size_t)mc * 6144 + c * 16 + mi]        = h;
    ES[(size_t)mc * 6144 + 3072 + c * 16 + mi] = l;
}

__global__ void winit_k(float* __restrict__ wr, float* __restrict__ wi) {
    const int m = blockIdx.x * 256 + threadIdx.x;
    wr[m] = 1.f; wi[m] = 0.f;
}

// ---------------------------------------------------------------------------
// Adjoint pure GEMM: outP[s][x,y] = sum_{m in split s} E[m,x]*conj(B[m,y]).
// 4608 one-wave blocks (128 splits x 9 tiles x 4 sub-tiles of 32x32).
// Per chunk: 8 batch-issued global_load_dwordx4 (each a contiguous 1KB
// fragment), sched_barrier, 24 MFMA. No LDS / barriers / pipeline; latency
// hidden by 4 waves/SIMD TLP. XCD swizzle: 16 splits per XCD (L2-local).
__global__ __launch_bounds__(64, 4) void adj_gemm_k(
    const unsigned* __restrict__ ES, const unsigned* __restrict__ BS,
    float* __restrict__ outP)
{
    const int lane = threadIdx.x & 63;
    const int l15 = lane & 15, qd = lane >> 4;
    const int L = blockIdx.x;                      // 0..4607, XCD swizzle
    const int xcd = L & 7, j = L >> 3;             // j 0..575
    const int s = xcd * (SPLITS / 8) + j / 36;     // split 0..127
    const int r = j % 36;                          // 9 tiles x 4 sub-tiles
    const int tile = r >> 2, wid = r & 3;
    const int bx = tile % 3, by = tile / 3;
    const int wi = wid & 1, wj = wid >> 1;
    const int x0 = bx * 64 + wi * 32, y0 = by * 64 + wj * 32;
    float* outRe = outP + (size_t)s * (2 * MTOT);
    float* outIm = outRe + MTOT;

    // lane word-offsets of the 16B fragment loads within a chunk
    const int eo0 = (x0 + l15) * 16 + qd * 4;
    const int eo1 = eo0 + 256;                     // +16 coords
    const int bo0 = (y0 + l15) * 16 + qd * 4;
    const int bo1 = bo0 + 256;

    const unsigned* Ep = ES + (size_t)(s * ADJ_CHUNKS) * 6144;
    const unsigned* Bp = BS + (size_t)(s * ADJ_CHUNKS) * 6144;

    f32x4 accRe[2][2], accIm[2][2];
    #pragma unroll
    for (int i = 0; i < 2; ++i)
        #pragma unroll
        for (int j2 = 0; j2 < 2; ++j2) {
            accRe[i][j2] = (f32x4){0.f, 0.f, 0.f, 0.f};
            accIm[i][j2] = (f32x4){0.f, 0.f, 0.f, 0.f};
        }

    #pragma unroll 1
    for (int ch = 0; ch < ADJ_CHUNKS; ++ch) {
        // batch-issue all 8 fragment loads for this chunk
        const u32x4 Eh0 = *(const u32x4*)(Ep + eo0);
        const u32x4 Eh1 = *(const u32x4*)(Ep + eo1);
        const u32x4 El0 = *(const u32x4*)(Ep + 3072 + eo0);
        const u32x4 El1 = *(const u32x4*)(Ep + 3072 + eo1);
        const u32x4 Ph0 = *(const u32x4*)(Bp + bo0);
        const u32x4 Ph1 = *(const u32x4*)(Bp + bo1);
        const u32x4 Pl0 = *(const u32x4*)(Bp + 3072 + bo0);
        const u32x4 Pl1 = *(const u32x4*)(Bp + 3072 + bo1);
        __builtin_amdgcn_sched_barrier(0);         // loads above, compute below

        #pragma unroll
        for (int sj = 0; sj < 2; ++sj) {
            const u32x4 Ph = sj ? Ph1 : Ph0;
            const u32x4 Pl = sj ? Pl1 : Pl0;
            u32x4 Qh, Ql;
            #pragma unroll
            for (int rr = 0; rr < 4; ++rr) {
                Qh[rr] = rot16(Ph[rr]) ^ 0x00008000u;      // (sb, cb)
                Ql[rr] = rot16(Pl[rr]) ^ 0x00008000u;
            }
            #pragma unroll
            for (int si = 0; si < 2; ++si) {
                const u32x4 Eh = si ? Eh1 : Eh0;
                const u32x4 El = si ? El1 : El0;
                accRe[si][sj] = mfma_bf16(Eh, Ph, accRe[si][sj]);
                accRe[si][sj] = mfma_bf16(Eh, Pl, accRe[si][sj]);
                accRe[si][sj] = mfma_bf16(El, Ph, accRe[si][sj]);
                accIm[si][sj] = mfma_bf16(Eh, Qh, accIm[si][sj]);
                accIm[si][sj] = mfma_bf16(Eh, Ql, accIm[si][sj]);
                accIm[si][sj] = mfma_bf16(El, Qh, accIm[si][sj]);
            }
        }
        Ep += 6144; Bp += 6144;
    }

    // epilogue: PLAIN stores -- wave exclusively owns tile (s, x0.., y0..)
    #pragma unroll
    for (int si = 0; si < 2; ++si)
        #pragma unroll
        for (int sj = 0; sj < 2; ++sj)
            #pragma unroll
            for (int rg = 0; rg < 4; ++rg) {
                const int x = x0 + si * 16 + qd * 4 + rg;   // C/D row
                const int y = y0 + sj * 16 + l15;           // C/D col
                outRe[x * NPIX + y] = accRe[si][sj][rg];
                outIm[x * NPIX + y] = accIm[si][sj][rg];
            }
}

// ---------------------------------------------------------------------------
// fwdq: q[m] = sum_x A[m,x] * (sum_y B[m,y]*g[x,y]).   (round-0 form, best
// measured ~46us: 576 thr, 60KB LDS, reg-staged double buffer, 2 barriers.)
__device__ __forceinline__ void fw_stage_load(const unsigned* __restrict__ Ghi,
                                              const unsigned* __restrict__ Glo,
                                              int tid, int koff, u32x4 st[3]) {
    #pragma unroll
    for (int j = 0; j < 3; ++j) {
        const int li = tid + j * 576;
        if (li < 1536) {
            const int row = li >> 3, pl = (li >> 2) & 1, qt = li & 3;
            const unsigned* src = pl ? Glo : Ghi;
            st[j] = *(const u32x4*)(src + row * 192 + koff + qt * 4);
        }
    }
}
__device__ __forceinline__ void fw_stage_write(unsigned* sb, int tid, const u32x4 st[3]) {
    #pragma unroll
    for (int j = 0; j < 3; ++j) {
        const int li = tid + j * 576;
        if (li < 1536) {
            const int row = li >> 3, pl = (li >> 2) & 1, qt = li & 3;
            *(u32x4*)(sb + pl * 3840 + row * 20 + qt * 4) = st[j];
        }
    }
}

__global__ __launch_bounds__(576) void fwdq_k(
    const float* __restrict__ traj,
    const unsigned* __restrict__ Ghi, const unsigned* __restrict__ Glo,
    float* __restrict__ wre, float* __restrict__ wim,
    const int mode,
    float* __restrict__ qre, float* __restrict__ qim)
{
    __shared__ unsigned sG[2][2 * 3840];   // 60 KB
    const int tid = threadIdx.x;
    const int lane = tid & 63, wid = tid >> 6;         // wid 0..8
    const int l15 = lane & 15, q = lane >> 4;
    const int m = (blockIdx.x * 9 + wid) * 16 + l15;
    const float2 kk = *(const float2*)(traj + 2 * m);
    float kxh, kxl, kyh, kyl;
    ksplit(kk.x, kxh, kxl);
    ksplit(kk.y, kyh, kyl);

    f32x4 tre[12], tim[12];
    #pragma unroll
    for (int i = 0; i < 12; ++i) {
        tre[i] = (f32x4){0.f, 0.f, 0.f, 0.f};
        tim[i] = (f32x4){0.f, 0.f, 0.f, 0.f};
    }

    float bc, bs;
    { const float ph = redphase(kyh, kyl, (float)(q * 4 - 96)); 
      bc = __builtin_amdgcn_cosf(ph); bs = __builtin_amdgcn_sinf(ph); }
    const float r1c = __builtin_amdgcn_cosf(kk.y), r1s = __builtin_amdgcn_sinf(kk.y);
    float r16c, r16s;
    { float g = kk.y * 16.f; g -= rintf(g);
      r16c = __builtin_amdgcn_cosf(g); r16s = __builtin_amdgcn_sinf(g); }

    u32x4 st[3];
    fw_stage_load(Ghi, Glo, tid, 0, st);
    fw_stage_write(&sG[0][0], tid, st);
    __syncthreads();

    for (int ch = 0; ch < 12; ++ch) {
        if (ch < 11) fw_stage_load(Ghi, Glo, tid, (ch + 1) * 16, st);

        u32x4 Ph, Pl, Qh, Ql;
        {
            float c = bc, s = bs;
            #pragma unroll
            for (int r = 0; r < 4; ++r) {
                unsigned h, l; split_pk(c, s, h, l);
                Ph[r] = h; Pl[r] = l;
                Qh[r] = rot16(h) ^ 0x00008000u;
                Ql[r] = rot16(l) ^ 0x00008000u;
                const float nc = c * r1c - s * r1s, ns = s * r1c + c * r1s;
                c = nc; s = ns;
            }
            const float nbc = bc * r16c - bs * r16s, nbs = bs * r16c + bc * r16s;
            bc = nbc; bs = nbs;
        }

        const unsigned* sb = &sG[ch & 1][0];
        #pragma unroll
        for (int si = 0; si < 12; ++si) {
            const int base = (si * 16 + l15) * 20 + q * 4;
            const u32x4 gh = *(const u32x4*)(sb + base);
            const u32x4 gl = *(const u32x4*)(sb + 3840 + base);
            tre[si] = mfma_bf16(gh, Ph, tre[si]);
            tre[si] = mfma_bf16(gh, Pl, tre[si]);
            tre[si] = mfma_bf16(gl, Ph, tre[si]);
            tim[si] = mfma_bf16(gh, Qh, tim[si]);
            tim[si] = mfma_bf16(gh, Ql, tim[si]);
            tim[si] = mfma_bf16(gl, Qh, tim[si]);
        }

        if (ch < 11) {
            __syncthreads();
            fw_stage_write(&sG[(ch + 1) & 1][0], tid, st);
            __syncthreads();
        }
    }

    float qr = 0.f, qi = 0.f;
    {
        float g = kk.x * 16.f; g -= rintf(g);
        const float rc = __builtin_amdgcn_cosf(g), rs = __builtin_amdgcn_sinf(g);
        #pragma unroll
        for (int rg = 0; rg < 4; ++rg) {
            const float ph = redphase(kxh, kxl, (float)(q * 4 + rg - 96));
            float c = __builtin_amdgcn_cosf(ph), s = __builtin_amdgcn_sinf(ph);
            #pragma unroll
            for (int si = 0; si < 12; ++si) {
                const float tr = tre[si][rg], ti = tim[si][rg];
                qr += c * tr + s * ti;
                qi += c * ti - s * tr;
                const float nc = c * rc - s * rs, ns = s * rc + c * rs;
                c = nc; s = ns;
            }
        }
    }
    qr += __shfl_xor(qr, 16); qi += __shfl_xor(qi, 16);
    qr += __shfl_xor(qr, 32); qi += __shfl_xor(qi, 32);
    if (lane < 16) {
        if (mode == 0) {
            const float den = fmaxf(sqrtf(qr * qr + qi * qi), 1e-20f);
            wre[m] /= den; wim[m] /= den;
        } else {
            const float sc = sqrtf(wre[m] * wre[m] + wim[m] * wim[m]);
            qre[m] = qr * sc; qim[m] = qi * sc;
        }
    }
}

// ---------------------------------------------------------------------------
__global__ void presplit_k(const float* __restrict__ re, const float* __restrict__ im,
                           unsigned* __restrict__ Gh, unsigned* __restrict__ Gl) {
    const int e = blockIdx.x * 256 + threadIdx.x;
    unsigned h, l;
    split_pk(re[e], im[e], h, l);     // low16 = re (even K), high16 = im (odd K)
    Gh[e] = h; Gl[e] = l;
}

// Reduce PG partial images + presplit (pipe path)
__global__ void presplitP_k(const float* __restrict__ outP,
                            unsigned* __restrict__ Gh, unsigned* __restrict__ Gl) {
    const int e = blockIdx.x * 256 + threadIdx.x;
    float re = 0.f, im = 0.f;
    #pragma unroll 8
    for (int g = 0; g < PG; ++g) {
        re += outP[(size_t)g * (2 * MTOT) + e];
        im += outP[(size_t)g * (2 * MTOT) + MTOT + e];
    }
    unsigned h, l;
    split_pk(re, im, h, l);
    Gh[e] = h; Gl[e] = l;
}

// Reduce PG partial images -> final output
__global__ void reduceOut_k(const float* __restrict__ outP, float* __restrict__ out) {
    const int e = blockIdx.x * 256 + threadIdx.x;
    float re = 0.f, im = 0.f;
    #pragma unroll 8
    for (int g = 0; g < PG; ++g) {
        re += outP[(size_t)g * (2 * MTOT) + e];
        im += outP[(size_t)g * (2 * MTOT) + MTOT + e];
    }
    out[e] = re; out[MTOT + e] = im;
}

// ---------------------------------------------------------------------------
extern "C" void kernel_launch(void* const* d_in, const int* in_sizes, int n_in,
                              void* d_out, int out_size, void* d_ws, size_t ws_size,
                              hipStream_t stream)
{
    const float* xin  = (const float*)d_in[0];   // (2,192,192)
    const float* traj = (const float*)d_in[1];   // (36864,2)
    float* out = (float*)d_out;                  // (2,192,192)

    char* pb = (char*)d_ws;
    unsigned* BS = (unsigned*)pb; pb += (size_t)2304 * 6144 * 4;   // 56.6 MB
    unsigned* ES = (unsigned*)pb; pb += (size_t)2304 * 6144 * 4;   // 56.6 MB
    float* outP = (float*)pb; pb += (size_t)PG * 2 * MTOT * 4;     // 37.8 MB
    float* wr   = (float*)pb; pb += MTOT * 4;
    float* wi   = (float*)pb; pb += MTOT * 4;
    float* dre  = (float*)pb; pb += MTOT * 4;
    float* dim_ = (float*)pb; pb += MTOT * 4;
    unsigned* Ghi = (unsigned*)pb; pb += MTOT * 4;
    unsigned* Glo = (unsigned*)pb; pb += MTOT * 4;

    precompP_k<<<dim3(MTOT / 256, NPIX), 256, 0, stream>>>(traj, 1, BS);
    winit_k<<<MTOT / 256, 256, 0, stream>>>(wr, wi);

    for (int it = 0; it < 3; ++it) {
        ebuild_k<<<dim3(MTOT / 256, NPIX), 256, 0, stream>>>(traj, wr, wi, ES);
        adj_gemm_k<<<36 * SPLITS, 64, 0, stream>>>(ES, BS, outP);
        presplitP_k<<<MTOT / 256, 256, 0, stream>>>(outP, Ghi, Glo);
        fwdq_k<<<256, 576, 0, stream>>>(traj, Ghi, Glo, wr, wi, 0, dre, dim_);
    }

    presplit_k<<<MTOT / 256, 256, 0, stream>>>(xin, xin + MTOT, Ghi, Glo);
    fwdq_k<<<256, 576, 0, stream>>>(traj, Ghi, Glo, wr, wi, 1, dre, dim_);
    ebuild_k<<<dim3(MTOT / 256, NPIX), 256, 0, stream>>>(traj, dre, dim_, ES);
    adj_gemm_k<<<36 * SPLITS, 64, 0, stream>>>(ES, BS, outP);
    reduceOut_k<<<MTOT / 256, 256, 0, stream>>>(outP, out);
}

// Round 9
// 459.897 us; speedup vs baseline: 1.1445x; 1.1068x over previous
//
#include <hip/hip_runtime.h>
#include <math.h>

// Radial NUFFT + Pipe-Menon density compensation, MI355X (gfx950).
// bf16 MFMA (16x16x32), 2-term hi/lo split (3 products). Round 23 = exact
// r18 restoration (measured best 463us: atomic-free adj, PG=64, 576 blocks
// x 36 chunks, triple-buffer counted-vmcnt pipeline; round-0 fwdq) + ONE
// proven-safe delta: fwdq single barrier per chunk. WAR proof: ds_write
// targets buf[(ch+1)&1]; all waves in iter ch read only buf[ch&1]; a wave
// still reading buf[(ch+1)&1] would be in iter ch-1, impossible past the
// end-of-(ch-1) barrier. So [write; sync] replaces [sync; write; sync].
// adj keeps 2 barriers (the same transform is UNSAFE there: STAGE DMA
// would race other waves' ds_reads -- r21 evidence).

#define MTOT 36864      // N_SHOTS*N_SAMPLES == NPIX*NPIX
#define NPIX 192
#define SPLITS 128
#define GRP 64                  // split-groups: block g covers splits {g, g+64}
#define NCH 36                  // 2 splits x 18 chunks of 16 m
#define PG 64                   // privatized partial images (one per group)

typedef __attribute__((ext_vector_type(8))) short s16x8;
typedef __attribute__((ext_vector_type(4))) float f32x4;
typedef __attribute__((ext_vector_type(4))) unsigned u32x4;

__device__ __forceinline__ f32x4 mfma_bf16(u32x4 a, u32x4 b, f32x4 c) {
    return __builtin_amdgcn_mfma_f32_16x16x32_bf16(
        __builtin_bit_cast(s16x8, a), __builtin_bit_cast(s16x8, b), c, 0, 0, 0);
}

// async 16B/lane global->LDS (DMA); LDS dest = wave-uniform base + lane*16.
__device__ __forceinline__ void g2l16(const void* g, void* l) {
    __builtin_amdgcn_global_load_lds(
        (const __attribute__((address_space(1))) void*)g,
        (__attribute__((address_space(3))) void*)l, 16, 0, 0);
}

// Split (a,b) into packed bf16 pairs: hi = (bf16(a) | bf16(b)<<16), lo = residuals.
__device__ __forceinline__ void split_pk(float a, float b, unsigned &hi, unsigned &lo) {
    const unsigned ua = __float_as_uint(a), ub = __float_as_uint(b);
    const unsigned ha = (ua + 0x8000u) & 0xffff0000u;
    const unsigned hb = (ub + 0x8000u) & 0xffff0000u;
    hi = (ha >> 16) | hb;
    const float la = a - __uint_as_float(ha);
    const float lb = b - __uint_as_float(hb);
    lo = ((__float_as_uint(la) + 0x8000u) >> 16) |
         ((__float_as_uint(lb) + 0x8000u) & 0xffff0000u);
}

// k split into 12-bit hi + residual so kh*p (p integer, |p|<=96) is EXACT in fp32.
__device__ __forceinline__ void ksplit(float k, float &kh, float &kl) {
    kh = __uint_as_float(__float_as_uint(k) & 0xfffff000u);
    kl = k - kh;
}
__device__ __forceinline__ float redphase(float kh, float kl, float p) {
    float r = kh * p;
    r -= rintf(r);
    r = fmaf(kl, p, r);
    return r;                   // revolutions, |r| <= ~0.512
}
__device__ __forceinline__ unsigned rot16(unsigned v) {
    return __builtin_amdgcn_alignbit(v, v, 16);
}
__device__ __forceinline__ int swz(int c) {        // bank swizzle (r10-verified)
    return ((c ^ (c >> 2)) & 3) << 2;
}

// ---------------------------------------------------------------------------
// Precompute packed B phasor (cos, -sin) hi/lo, chunk-contiguous + swizzled:
// PS[mc][plane][c(192)][mi^swz(c)]  (r10-verified layout).
__global__ void precompP_k(const float* __restrict__ traj, const int comp,
                           unsigned* __restrict__ PS) {
    const int m = blockIdx.x * 256 + threadIdx.x;
    const int c = blockIdx.y;
    float kh, kl; ksplit(traj[2 * m + comp], kh, kl);
    const float ph = redphase(kh, kl, (float)(c - 96));
    const float co = __builtin_amdgcn_cosf(ph);
    const float si = __builtin_amdgcn_sinf(ph);
    unsigned h, l; split_pk(co, -si, h, l);
    const int mc = m >> 4, mi = (m & 15) ^ swz(c);
    PS[(size_t)mc * 6144 + c * 16 + mi]        = h;
    PS[(size_t)mc * 6144 + 3072 + c * 16 + mi] = l;
}

// E[m,x] = conj(A[m,x]) * d[m], packed bf16 hi/lo, same swizzled layout.
__global__ void ebuild_k(const float* __restrict__ traj,
                         const float* __restrict__ dr, const float* __restrict__ di,
                         unsigned* __restrict__ ES) {
    const int m = blockIdx.x * 256 + threadIdx.x;
    const int c = blockIdx.y;                        // x coordinate
    float kh, kl; ksplit(traj[2 * m], kh, kl);
    const float ph = redphase(kh, kl, (float)(c - 96));
    const float co = __builtin_amdgcn_cosf(ph);
    const float si = __builtin_amdgcn_sinf(ph);
    const float dr_ = dr[m], di_ = di[m];
    const float Er = co * dr_ - si * di_;
    const float Ei = co * di_ + si * dr_;
    unsigned h, l; split_pk(Er, Ei, h, l);
    const int mc = m >> 4, mi = (m & 15) ^ swz(c);
    ES[(size_t)mc * 6144 + c * 16 + mi]        = h;
    ES[(size_t)mc * 6144 + 3072 + c * 16 + mi] = l;
}

__global__ void winit_k(float* __restrict__ wr, float* __restrict__ wi) {
    const int m = blockIdx.x * 256 + threadIdx.x;
    wr[m] = 1.f; wi[m] = 0.f;
}

// ---------------------------------------------------------------------------
// Adjoint pure GEMM (r18, measured best): outP[g][x,y] = sum_{m in g,g+64}.
// 576 blocks (64 groups x 9 tiles) of 4 waves; block owns a 64x64 tile of
// image g EXCLUSIVELY -> plain stores, zero atomics. 3 LDS buffers, stage
// chunk ch+2 while computing ch, barrier#1 after counted vmcnt(8), barrier#2
// after lgkmcnt(0) closes the WAR. 36 continuous chunks (id jumps +1134 at
// the split boundary) so the pipeline never drains mid-block.
__global__ __launch_bounds__(256) void adj_gemm_k(
    const unsigned* __restrict__ ES, const unsigned* __restrict__ BS,
    float* __restrict__ outP)
{
    __shared__ unsigned sAB[3][4096];              // 48 KB triple buffer
    const int tid = threadIdx.x;
    const int lane = tid & 63, wid = tid >> 6;     // wid 0..3
    const int l15 = lane & 15, qd = lane >> 4;
    const int L = blockIdx.x;                      // 0..575, XCD swizzle
    const int xcd = L & 7, j = L >> 3;             // j 0..71
    const int g = xcd * (GRP / 8) + j / 9;         // split-group 0..63
    const int tile = j % 9;
    const int bx = tile % 3, by = tile / 3;
    const int wi = wid & 1, wj = wid >> 1;
    const int x0 = bx * 64 + wi * 32, y0 = by * 64 + wj * 32;
    float* outRe = outP + (size_t)g * (2 * MTOT);
    float* outIm = outRe + MTOT;

    f32x4 accRe[2][2], accIm[2][2];
    #pragma unroll
    for (int i = 0; i < 2; ++i)
        #pragma unroll
        for (int j2 = 0; j2 < 2; ++j2) {
            accRe[i][j2] = (f32x4){0.f, 0.f, 0.f, 0.f};
            accIm[i][j2] = (f32x4){0.f, 0.f, 0.f, 0.f};
        }

    // staging: chunk c of this block = split (g + 64*(c>=18)), local chunk c%18
    const size_t g18 = (size_t)g * 18;
    const int exo = bx * 1024 + tid * 4;           // E rows [bx*64..+64)
    const int byo = by * 1024 + tid * 4;           // B rows [by*64..+64)
    #define STAGE(c, buf)                                                  \
    {                                                                      \
        const size_t id_ = (g18 + (c) + (((c) >= 18) ? 1134 : 0)) * 6144; \
        const unsigned* E0_ = ES + id_;                                    \
        const unsigned* B0_ = BS + id_;                                    \
        g2l16(E0_ + exo,        &sAB[buf][tid * 4]);                       \
        g2l16(E0_ + 3072 + exo, &sAB[buf][1024 + tid * 4]);                \
        g2l16(B0_ + byo,        &sAB[buf][2048 + tid * 4]);                \
        g2l16(B0_ + 3072 + byo, &sAB[buf][3072 + tid * 4]);                \
    }

    // fragment LDS word offsets within a buffer (local coord; swz(local)==swz(global))
    int eoff[2], boff[2];
    #pragma unroll
    for (int t = 0; t < 2; ++t) {
        const int cE = wi * 32 + t * 16 + l15;     // local x coord 0..63
        eoff[t] = cE * 16 + ((qd ^ ((cE ^ (cE >> 2)) & 3)) << 2);
        const int cB = wj * 32 + t * 16 + l15;     // local y coord 0..63
        boff[t] = 2048 + cB * 16 + ((qd ^ ((cB ^ (cB >> 2)) & 3)) << 2);
    }

    STAGE(0, 0);                                   // prologue: chunks 0,1
    STAGE(1, 1);

    int rb = 0;                                    // read buffer = ch % 3
    for (int ch = 0; ch < NCH; ++ch) {
        if (ch + 2 < NCH) {                        // stage chunk ch+2
            const int wb = (rb + 2 >= 3) ? rb - 1 : rb + 2;   // (ch+2)%3
            STAGE(ch + 2, wb);
            // outstanding: ch(4), ch+1(4), ch+2(4); wait oldest 4 (chunk ch)
            asm volatile("s_waitcnt vmcnt(8)" ::: "memory");
        } else if (ch + 1 < NCH) {
            asm volatile("s_waitcnt vmcnt(4)" ::: "memory");
        } else {
            asm volatile("s_waitcnt vmcnt(0)" ::: "memory");
        }
        __builtin_amdgcn_s_barrier();              // buf rb ready block-wide

        const unsigned* sb = &sAB[rb][0];
        u32x4 Eh[2], El[2], PhA[2], PlA[2];
        #pragma unroll
        for (int t = 0; t < 2; ++t) {
            Eh[t]  = *(const u32x4*)(sb + eoff[t]);
            El[t]  = *(const u32x4*)(sb + 1024 + eoff[t]);
            PhA[t] = *(const u32x4*)(sb + boff[t]);
            PlA[t] = *(const u32x4*)(sb + 1024 + boff[t]);
        }
        asm volatile("s_waitcnt lgkmcnt(0)" ::: "memory");
        __builtin_amdgcn_sched_barrier(0);         // rule 18: pin MFMAs below
        __builtin_amdgcn_s_barrier();              // all waves done reading rb

        #pragma unroll
        for (int sj = 0; sj < 2; ++sj) {
            const u32x4 Ph = PhA[sj], Pl = PlA[sj];
            u32x4 Qh, Ql;
            #pragma unroll
            for (int r = 0; r < 4; ++r) {
                Qh[r] = rot16(Ph[r]) ^ 0x00008000u;                       // (sb, cb)
                Ql[r] = rot16(Pl[r]) ^ 0x00008000u;
            }
            #pragma unroll
            for (int si = 0; si < 2; ++si) {
                accRe[si][sj] = mfma_bf16(Eh[si], Ph, accRe[si][sj]);
                accRe[si][sj] = mfma_bf16(Eh[si], Pl, accRe[si][sj]);
                accRe[si][sj] = mfma_bf16(El[si], Ph, accRe[si][sj]);
                accIm[si][sj] = mfma_bf16(Eh[si], Qh, accIm[si][sj]);
                accIm[si][sj] = mfma_bf16(Eh[si], Ql, accIm[si][sj]);
                accIm[si][sj] = mfma_bf16(El[si], Qh, accIm[si][sj]);
            }
        }
        rb = (rb + 1 == 3) ? 0 : rb + 1;
    }
    #undef STAGE

    // epilogue: PLAIN stores -- block exclusively owns tile (g, x0.., y0..)
    #pragma unroll
    for (int si = 0; si < 2; ++si)
        #pragma unroll
        for (int sj = 0; sj < 2; ++sj)
            #pragma unroll
            for (int rg = 0; rg < 4; ++rg) {
                const int x = x0 + si * 16 + qd * 4 + rg;   // C/D row
                const int y = y0 + sj * 16 + l15;           // C/D col
                outRe[x * NPIX + y] = accRe[si][sj][rg];
                outIm[x * NPIX + y] = accIm[si][sj][rg];
            }
}

// ---------------------------------------------------------------------------
// fwdq: q[m] = sum_x A[m,x] * (sum_y B[m,y]*g[x,y]).  Round-0 form (best
// measured) with SINGLE barrier per chunk (WAR-safe, see header comment).
__device__ __forceinline__ void fw_stage_load(const unsigned* __restrict__ Ghi,
                                              const unsigned* __restrict__ Glo,
                                              int tid, int koff, u32x4 st[3]) {
    #pragma unroll
    for (int j = 0; j < 3; ++j) {
        const int li = tid + j * 576;
        if (li < 1536) {
            const int row = li >> 3, pl = (li >> 2) & 1, qt = li & 3;
            const unsigned* src = pl ? Glo : Ghi;
            st[j] = *(const u32x4*)(src + row * 192 + koff + qt * 4);
        }
    }
}
__device__ __forceinline__ void fw_stage_write(unsigned* sb, int tid, const u32x4 st[3]) {
    #pragma unroll
    for (int j = 0; j < 3; ++j) {
        const int li = tid + j * 576;
        if (li < 1536) {
            const int row = li >> 3, pl = (li >> 2) & 1, qt = li & 3;
            *(u32x4*)(sb + pl * 3840 + row * 20 + qt * 4) = st[j];
        }
    }
}

__global__ __launch_bounds__(576) void fwdq_k(
    const float* __restrict__ traj,
    const unsigned* __restrict__ Ghi, const unsigned* __restrict__ Glo,
    float* __restrict__ wre, float* __restrict__ wim,
    const int mode,
    float* __restrict__ qre, float* __restrict__ qim)
{
    __shared__ unsigned sG[2][2 * 3840];   // 60 KB
    const int tid = threadIdx.x;
    const int lane = tid & 63, wid = tid >> 6;         // wid 0..8
    const int l15 = lane & 15, q = lane >> 4;
    const int m = (blockIdx.x * 9 + wid) * 16 + l15;
    const float2 kk = *(const float2*)(traj + 2 * m);
    float kxh, kxl, kyh, kyl;
    ksplit(kk.x, kxh, kxl);
    ksplit(kk.y, kyh, kyl);

    f32x4 tre[12], tim[12];
    #pragma unroll
    for (int i = 0; i < 12; ++i) {
        tre[i] = (f32x4){0.f, 0.f, 0.f, 0.f};
        tim[i] = (f32x4){0.f, 0.f, 0.f, 0.f};
    }

    float bc, bs;
    { const float ph = redphase(kyh, kyl, (float)(q * 4 - 96)); 
      bc = __builtin_amdgcn_cosf(ph); bs = __builtin_amdgcn_sinf(ph); }
    const float r1c = __builtin_amdgcn_cosf(kk.y), r1s = __builtin_amdgcn_sinf(kk.y);
    float r16c, r16s;
    { float g = kk.y * 16.f; g -= rintf(g);
      r16c = __builtin_amdgcn_cosf(g); r16s = __builtin_amdgcn_sinf(g); }

    u32x4 st[3];
    fw_stage_load(Ghi, Glo, tid, 0, st);
    fw_stage_write(&sG[0][0], tid, st);
    __syncthreads();

    for (int ch = 0; ch < 12; ++ch) {
        if (ch < 11) fw_stage_load(Ghi, Glo, tid, (ch + 1) * 16, st);

        u32x4 Ph, Pl, Qh, Ql;
        {
            float c = bc, s = bs;
            #pragma unroll
            for (int r = 0; r < 4; ++r) {
                unsigned h, l; split_pk(c, s, h, l);
                Ph[r] = h; Pl[r] = l;
                Qh[r] = rot16(h) ^ 0x00008000u;
                Ql[r] = rot16(l) ^ 0x00008000u;
                const float nc = c * r1c - s * r1s, ns = s * r1c + c * r1s;
                c = nc; s = ns;
            }
            const float nbc = bc * r16c - bs * r16s, nbs = bs * r16c + bc * r16s;
            bc = nbc; bs = nbs;
        }

        const unsigned* sb = &sG[ch & 1][0];
        #pragma unroll
        for (int si = 0; si < 12; ++si) {
            const int base = (si * 16 + l15) * 20 + q * 4;
            const u32x4 gh = *(const u32x4*)(sb + base);
            const u32x4 gl = *(const u32x4*)(sb + 3840 + base);
            tre[si] = mfma_bf16(gh, Ph, tre[si]);
            tre[si] = mfma_bf16(gh, Pl, tre[si]);
            tre[si] = mfma_bf16(gl, Ph, tre[si]);
            tim[si] = mfma_bf16(gh, Qh, tim[si]);
            tim[si] = mfma_bf16(gh, Ql, tim[si]);
            tim[si] = mfma_bf16(gl, Qh, tim[si]);
        }

        if (ch < 11) {
            // write targets buf[(ch+1)&1]; every wave in iter ch reads only
            // buf[ch&1]; stragglers in iter ch-1 are impossible past the
            // previous barrier -> no WAR. Single RAW barrier after the write.
            fw_stage_write(&sG[(ch + 1) & 1][0], tid, st);
            __syncthreads();
        }
    }

    float qr = 0.f, qi = 0.f;
    {
        float g = kk.x * 16.f; g -= rintf(g);
        const float rc = __builtin_amdgcn_cosf(g), rs = __builtin_amdgcn_sinf(g);
        #pragma unroll
        for (int rg = 0; rg < 4; ++rg) {
            const float ph = redphase(kxh, kxl, (float)(q * 4 + rg - 96));
            float c = __builtin_amdgcn_cosf(ph), s = __builtin_amdgcn_sinf(ph);
            #pragma unroll
            for (int si = 0; si < 12; ++si) {
                const float tr = tre[si][rg], ti = tim[si][rg];
                qr += c * tr + s * ti;
                qi += c * ti - s * tr;
                const float nc = c * rc - s * rs, ns = s * rc + c * rs;
                c = nc; s = ns;
            }
        }
    }
    qr += __shfl_xor(qr, 16); qi += __shfl_xor(qi, 16);
    qr += __shfl_xor(qr, 32); qi += __shfl_xor(qi, 32);
    if (lane < 16) {
        if (mode == 0) {
            const float den = fmaxf(sqrtf(qr * qr + qi * qi), 1e-20f);
            wre[m] /= den; wim[m] /= den;
        } else {
            const float sc = sqrtf(wre[m] * wre[m] + wim[m] * wim[m]);
            qre[m] = qr * sc; qim[m] = qi * sc;
        }
    }
}

// ---------------------------------------------------------------------------
__global__ void presplit_k(const float* __restrict__ re, const float* __restrict__ im,
                           unsigned* __restrict__ Gh, unsigned* __restrict__ Gl) {
    const int e = blockIdx.x * 256 + threadIdx.x;
    unsigned h, l;
    split_pk(re[e], im[e], h, l);     // low16 = re (even K), high16 = im (odd K)
    Gh[e] = h; Gl[e] = l;
}

// Reduce PG partial images + presplit (pipe path)
__global__ void presplitP_k(const float* __restrict__ outP,
                            unsigned* __restrict__ Gh, unsigned* __restrict__ Gl) {
    const int e = blockIdx.x * 256 + threadIdx.x;
    float re = 0.f, im = 0.f;
    #pragma unroll 8
    for (int g = 0; g < PG; ++g) {
        re += outP[(size_t)g * (2 * MTOT) + e];
        im += outP[(size_t)g * (2 * MTOT) + MTOT + e];
    }
    unsigned h, l;
    split_pk(re, im, h, l);
    Gh[e] = h; Gl[e] = l;
}

// Reduce PG partial images -> final output
__global__ void reduceOut_k(const float* __restrict__ outP, float* __restrict__ out) {
    const int e = blockIdx.x * 256 + threadIdx.x;
    float re = 0.f, im = 0.f;
    #pragma unroll 8
    for (int g = 0; g < PG; ++g) {
        re += outP[(size_t)g * (2 * MTOT) + e];
        im += outP[(size_t)g * (2 * MTOT) + MTOT + e];
    }
    out[e] = re; out[MTOT + e] = im;
}

// ---------------------------------------------------------------------------
extern "C" void kernel_launch(void* const* d_in, const int* in_sizes, int n_in,
                              void* d_out, int out_size, void* d_ws, size_t ws_size,
                              hipStream_t stream)
{
    const float* xin  = (const float*)d_in[0];   // (2,192,192)
    const float* traj = (const float*)d_in[1];   // (36864,2)
    float* out = (float*)d_out;                  // (2,192,192)

    char* pb = (char*)d_ws;
    unsigned* BS = (unsigned*)pb; pb += (size_t)2304 * 6144 * 4;   // 56.6 MB
    unsigned* ES = (unsigned*)pb; pb += (size_t)2304 * 6144 * 4;   // 56.6 MB
    float* outP = (float*)pb; pb += (size_t)PG * 2 * MTOT * 4;     // 18.9 MB
    float* wr   = (float*)pb; pb += MTOT * 4;
    float* wi   = (float*)pb; pb += MTOT * 4;
    float* dre  = (float*)pb; pb += MTOT * 4;
    float* dim_ = (float*)pb; pb += MTOT * 4;
    unsigned* Ghi = (unsigned*)pb; pb += MTOT * 4;
    unsigned* Glo = (unsigned*)pb; pb += MTOT * 4;

    precompP_k<<<dim3(MTOT / 256, NPIX), 256, 0, stream>>>(traj, 1, BS);
    winit_k<<<MTOT / 256, 256, 0, stream>>>(wr, wi);

    for (int it = 0; it < 3; ++it) {
        ebuild_k<<<dim3(MTOT / 256, NPIX), 256, 0, stream>>>(traj, wr, wi, ES);
        adj_gemm_k<<<9 * GRP, 256, 0, stream>>>(ES, BS, outP);
        presplitP_k<<<MTOT / 256, 256, 0, stream>>>(outP, Ghi, Glo);
        fwdq_k<<<256, 576, 0, stream>>>(traj, Ghi, Glo, wr, wi, 0, dre, dim_);
    }

    presplit_k<<<MTOT / 256, 256, 0, stream>>>(xin, xin + MTOT, Ghi, Glo);
    fwdq_k<<<256, 576, 0, stream>>>(traj, Ghi, Glo, wr, wi, 1, dre, dim_);
    ebuild_k<<<dim3(MTOT / 256, NPIX), 256, 0, stream>>>(traj, dre, dim_, ES);
    adj_gemm_k<<<9 * GRP, 256, 0, stream>>>(ES, BS, outP);
    reduceOut_k<<<MTOT / 256, 256, 0, stream>>>(outP, out);
}

// Round 10
// 457.694 us; speedup vs baseline: 1.1500x; 1.0048x over previous
//
#include <hip/hip_runtime.h>
#include <math.h>

// Radial NUFFT + Pipe-Menon density compensation, MI355X (gfx950).
// bf16 MFMA (16x16x32), 2-term hi/lo split (3 products). Round 24 = r23
// (session best 459.9us) + EBUILD FUSED INTO ADJ: the 4 ebuild_k dispatches
// (~44us total; 56.6MB HBM write + ~28MB read round-trip per iteration just
// to materialize E = conj(A)*d) are deleted. adj_gemm now computes its E
// fragments in-VALU one chunk ahead (8 transcendentals per thread-chunk,
// VALUBusy was only 29%) and writes them straight into LDS with the same
// r10 bank swizzle. B stays 3-deep global_load_lds DMA (counted vmcnt
// 4/2/0); E is 2-deep VALU-written (sE[(ch+1)&1] at iter ch -- WAR closed
// by barrier rendezvous: laggards' reads drained at their lgkmcnt(0) before
// arriving at barrier#1). Per-m (kx,dr,di) loaded once into a 6.9KB LDS
// table. LDS total 47KB -> 3 blocks/CU retained. E numerics are formula-
// identical to ebuild (same redphase/sincos/split_pk) -> same output.

#define MTOT 36864      // N_SHOTS*N_SAMPLES == NPIX*NPIX
#define NPIX 192
#define SPLITS 128
#define GRP 64                  // split-groups: block g covers splits {g, g+64}
#define NCH 36                  // 2 splits x 18 chunks of 16 m
#define PG 64                   // privatized partial images (one per group)

typedef __attribute__((ext_vector_type(8))) short s16x8;
typedef __attribute__((ext_vector_type(4))) float f32x4;
typedef __attribute__((ext_vector_type(4))) unsigned u32x4;

__device__ __forceinline__ f32x4 mfma_bf16(u32x4 a, u32x4 b, f32x4 c) {
    return __builtin_amdgcn_mfma_f32_16x16x32_bf16(
        __builtin_bit_cast(s16x8, a), __builtin_bit_cast(s16x8, b), c, 0, 0, 0);
}

// async 16B/lane global->LDS (DMA); LDS dest = wave-uniform base + lane*16.
__device__ __forceinline__ void g2l16(const void* g, void* l) {
    __builtin_amdgcn_global_load_lds(
        (const __attribute__((address_space(1))) void*)g,
        (__attribute__((address_space(3))) void*)l, 16, 0, 0);
}

// Split (a,b) into packed bf16 pairs: hi = (bf16(a) | bf16(b)<<16), lo = residuals.
__device__ __forceinline__ void split_pk(float a, float b, unsigned &hi, unsigned &lo) {
    const unsigned ua = __float_as_uint(a), ub = __float_as_uint(b);
    const unsigned ha = (ua + 0x8000u) & 0xffff0000u;
    const unsigned hb = (ub + 0x8000u) & 0xffff0000u;
    hi = (ha >> 16) | hb;
    const float la = a - __uint_as_float(ha);
    const float lb = b - __uint_as_float(hb);
    lo = ((__float_as_uint(la) + 0x8000u) >> 16) |
         ((__float_as_uint(lb) + 0x8000u) & 0xffff0000u);
}

// k split into 12-bit hi + residual so kh*p (p integer, |p|<=96) is EXACT in fp32.
__device__ __forceinline__ void ksplit(float k, float &kh, float &kl) {
    kh = __uint_as_float(__float_as_uint(k) & 0xfffff000u);
    kl = k - kh;
}
__device__ __forceinline__ float redphase(float kh, float kl, float p) {
    float r = kh * p;
    r -= rintf(r);
    r = fmaf(kl, p, r);
    return r;                   // revolutions, |r| <= ~0.512
}
__device__ __forceinline__ unsigned rot16(unsigned v) {
    return __builtin_amdgcn_alignbit(v, v, 16);
}
__device__ __forceinline__ int swz(int c) {        // bank swizzle (r10-verified)
    return ((c ^ (c >> 2)) & 3) << 2;
}

// ---------------------------------------------------------------------------
// Precompute packed B phasor (cos, -sin) hi/lo, chunk-contiguous + swizzled:
// PS[mc][plane][c(192)][mi^swz(c)]  (r10-verified layout).
__global__ void precompP_k(const float* __restrict__ traj, const int comp,
                           unsigned* __restrict__ PS) {
    const int m = blockIdx.x * 256 + threadIdx.x;
    const int c = blockIdx.y;
    float kh, kl; ksplit(traj[2 * m + comp], kh, kl);
    const float ph = redphase(kh, kl, (float)(c - 96));
    const float co = __builtin_amdgcn_cosf(ph);
    const float si = __builtin_amdgcn_sinf(ph);
    unsigned h, l; split_pk(co, -si, h, l);
    const int mc = m >> 4, mi = (m & 15) ^ swz(c);
    PS[(size_t)mc * 6144 + c * 16 + mi]        = h;
    PS[(size_t)mc * 6144 + 3072 + c * 16 + mi] = l;
}

__global__ void winit_k(float* __restrict__ wr, float* __restrict__ wi) {
    const int m = blockIdx.x * 256 + threadIdx.x;
    wr[m] = 1.f; wi[m] = 0.f;
}

// ---------------------------------------------------------------------------
// Adjoint pure GEMM + fused E-build:
// outP[g][x,y] = sum_{m in splits g,g+64} conj(A)[m,x]*d[m]*conj(B)[m,y].
// 576 blocks (64 groups x 9 tiles) of 4 waves; block owns a 64x64 tile of
// image g EXCLUSIVELY -> plain stores, zero atomics.
// Per chunk: B hi/lo via 2x g2l16 DMA (3-deep, counted vmcnt 4/2/0);
// E hi/lo computed in-VALU one chunk ahead into sE[(ch+1)&1] (thread t owns
// c=t>>2, mi-quad t&3: 3x ds_read_b128 from d-table, 4x sincos+cmul+split,
// 2x swizzled ds_write_b128). Barrier structure identical to r18/r23.
__global__ __launch_bounds__(256) void adj_gemm_k(
    const float* __restrict__ traj,
    const float* __restrict__ dr_g, const float* __restrict__ di_g,
    const unsigned* __restrict__ BS, float* __restrict__ outP)
{
    __shared__ unsigned sE[2][2048];               // 16 KB: E hi|lo, 2-deep
    __shared__ unsigned sB[3][2048];               // 24 KB: B hi|lo, 3-deep
    __shared__ float kxA[576], drA[576], diA[576]; // 6.9 KB d-table
    const int tid = threadIdx.x;
    const int lane = tid & 63, wid = tid >> 6;     // wid 0..3
    const int l15 = lane & 15, qd = lane >> 4;
    const int L = blockIdx.x;                      // 0..575, XCD swizzle
    const int xcd = L & 7, j = L >> 3;             // j 0..71
    const int g = xcd * (GRP / 8) + j / 9;         // split-group 0..63
    const int tile = j % 9;
    const int bx = tile % 3, by = tile / 3;
    const int wi = wid & 1, wj = wid >> 1;
    const int x0 = bx * 64 + wi * 32, y0 = by * 64 + wj * 32;
    float* outRe = outP + (size_t)g * (2 * MTOT);
    float* outIm = outRe + MTOT;

    // ---- one-time d-table fill: (kx, dr, di) for this block's 576 m ----
    #pragma unroll
    for (int rep = 0; rep < 3; ++rep) {
        const int idx = tid + rep * 256;
        if (idx < 576) {
            const int mg = (idx < 288) ? g * 288 + idx
                                       : (g + 64) * 288 + (idx - 288);
            kxA[idx] = traj[2 * mg];
            drA[idx] = dr_g[mg];
            diA[idx] = di_g[mg];
        }
    }

    f32x4 accRe[2][2], accIm[2][2];
    #pragma unroll
    for (int i = 0; i < 2; ++i)
        #pragma unroll
        for (int j2 = 0; j2 < 2; ++j2) {
            accRe[i][j2] = (f32x4){0.f, 0.f, 0.f, 0.f};
            accIm[i][j2] = (f32x4){0.f, 0.f, 0.f, 0.f};
        }

    // E-compute constants for this thread
    const int cE_ = tid >> 2;                      // local c 0..63
    const float pf = (float)(bx * 64 + cE_ - 96);  // pixel coord
    const int miq = tid & 3;                       // mi quad
    const int ewaddr = cE_ * 16 + ((miq ^ ((cE_ ^ (cE_ >> 2)) & 3)) << 2);

    // compute E for chunk (c) into sE[eb]
    #define ECOMP(c, eb)                                                   \
    {                                                                      \
        const int db = (c) * 16 + miq * 4;                                 \
        const f32x4 kx4 = *(const f32x4*)(kxA + db);                       \
        const f32x4 dr4 = *(const f32x4*)(drA + db);                       \
        const f32x4 di4 = *(const f32x4*)(diA + db);                       \
        u32x4 hv, lv;                                                      \
        _Pragma("unroll")                                                  \
        for (int jj = 0; jj < 4; ++jj) {                                   \
            float kh_, kl_; ksplit(kx4[jj], kh_, kl_);                     \
            const float ph_ = redphase(kh_, kl_, pf);                      \
            const float co_ = __builtin_amdgcn_cosf(ph_);                  \
            const float si_ = __builtin_amdgcn_sinf(ph_);                  \
            const float Er_ = co_ * dr4[jj] - si_ * di4[jj];               \
            const float Ei_ = co_ * di4[jj] + si_ * dr4[jj];               \
            unsigned h_, l_; split_pk(Er_, Ei_, h_, l_);                   \
            hv[jj] = h_; lv[jj] = l_;                                      \
        }                                                                  \
        *(u32x4*)(&sE[eb][ewaddr])        = hv;                            \
        *(u32x4*)(&sE[eb][1024 + ewaddr]) = lv;                            \
    }

    // B staging: chunk c of this block = split (g + 64*(c>=18)), local c%18
    const size_t g18 = (size_t)g * 18;
    const int byo = by * 1024 + tid * 4;           // B rows [by*64..+64)
    #define STAGEB(c, buf)                                                 \
    {                                                                      \
        const size_t id_ = (g18 + (c) + (((c) >= 18) ? 1134 : 0)) * 6144; \
        const unsigned* B0_ = BS + id_;                                    \
        g2l16(B0_ + byo,        &sB[buf][tid * 4]);                        \
        g2l16(B0_ + 3072 + byo, &sB[buf][1024 + tid * 4]);                 \
    }

    // fragment LDS word offsets (local coord; swz(local)==swz(global))
    int eoff[2], boff[2];
    #pragma unroll
    for (int t = 0; t < 2; ++t) {
        const int cE = wi * 32 + t * 16 + l15;     // local x coord 0..63
        eoff[t] = cE * 16 + ((qd ^ ((cE ^ (cE >> 2)) & 3)) << 2);
        const int cB = wj * 32 + t * 16 + l15;     // local y coord 0..63
        boff[t] = cB * 16 + ((qd ^ ((cB ^ (cB >> 2)) & 3)) << 2);
    }

    STAGEB(0, 0);                                  // prologue: B chunks 0,1
    STAGEB(1, 1);
    __syncthreads();                               // d-table visible block-wide
    ECOMP(0, 0);                                   // E chunk 0
    asm volatile("s_waitcnt lgkmcnt(0)" ::: "memory");   // E(0) writes drained

    for (int ch = 0; ch < NCH; ++ch) {
        if (ch + 2 < NCH) {                        // stage B chunk ch+2
            const int rb3 = ch % 3;
            const int wb = (rb3 + 2 >= 3) ? rb3 - 1 : rb3 + 2;  // (ch+2)%3
            STAGEB(ch + 2, wb);
            // outstanding: B(ch)2, B(ch+1)2, B(ch+2)2; wait oldest 2
            asm volatile("s_waitcnt vmcnt(4)" ::: "memory");
        } else if (ch + 1 < NCH) {
            asm volatile("s_waitcnt vmcnt(2)" ::: "memory");
        } else {
            asm volatile("s_waitcnt vmcnt(0)" ::: "memory");
        }
        __builtin_amdgcn_s_barrier();              // buffers for ch ready

        if (ch + 1 < NCH) ECOMP(ch + 1, (ch + 1) & 1);   // E one chunk ahead

        const unsigned* se = &sE[ch & 1][0];
        const unsigned* sb = &sB[ch % 3][0];
        u32x4 Eh[2], El[2], PhA[2], PlA[2];
        #pragma unroll
        for (int t = 0; t < 2; ++t) {
            Eh[t]  = *(const u32x4*)(se + eoff[t]);
            El[t]  = *(const u32x4*)(se + 1024 + eoff[t]);
            PhA[t] = *(const u32x4*)(sb + boff[t]);
            PlA[t] = *(const u32x4*)(sb + 1024 + boff[t]);
        }
        asm volatile("s_waitcnt lgkmcnt(0)" ::: "memory");
        __builtin_amdgcn_sched_barrier(0);         // rule 18: pin MFMAs below
        __builtin_amdgcn_s_barrier();              // all waves done reading

        #pragma unroll
        for (int sj = 0; sj < 2; ++sj) {
            const u32x4 Ph = PhA[sj], Pl = PlA[sj];
            u32x4 Qh, Ql;
            #pragma unroll
            for (int r = 0; r < 4; ++r) {
                Qh[r] = rot16(Ph[r]) ^ 0x00008000u;                       // (sb, cb)
                Ql[r] = rot16(Pl[r]) ^ 0x00008000u;
            }
            #pragma unroll
            for (int si = 0; si < 2; ++si) {
                accRe[si][sj] = mfma_bf16(Eh[si], Ph, accRe[si][sj]);
                accRe[si][sj] = mfma_bf16(Eh[si], Pl, accRe[si][sj]);
                accRe[si][sj] = mfma_bf16(El[si], Ph, accRe[si][sj]);
                accIm[si][sj] = mfma_bf16(Eh[si], Qh, accIm[si][sj]);
                accIm[si][sj] = mfma_bf16(Eh[si], Ql, accIm[si][sj]);
                accIm[si][sj] = mfma_bf16(El[si], Qh, accIm[si][sj]);
            }
        }
    }
    #undef ECOMP
    #undef STAGEB

    // epilogue: PLAIN stores -- block exclusively owns tile (g, x0.., y0..)
    #pragma unroll
    for (int si = 0; si < 2; ++si)
        #pragma unroll
        for (int sj = 0; sj < 2; ++sj)
            #pragma unroll
            for (int rg = 0; rg < 4; ++rg) {
                const int x = x0 + si * 16 + qd * 4 + rg;   // C/D row
                const int y = y0 + sj * 16 + l15;           // C/D col
                outRe[x * NPIX + y] = accRe[si][sj][rg];
                outIm[x * NPIX + y] = accIm[si][sj][rg];
            }
}

// ---------------------------------------------------------------------------
// fwdq: q[m] = sum_x A[m,x] * (sum_y B[m,y]*g[x,y]).  r23 form (proven):
// 576 thr, 60KB LDS, reg-staged double buffer, SINGLE barrier per chunk.
__device__ __forceinline__ void fw_stage_load(const unsigned* __restrict__ Ghi,
                                              const unsigned* __restrict__ Glo,
                                              int tid, int koff, u32x4 st[3]) {
    #pragma unroll
    for (int j = 0; j < 3; ++j) {
        const int li = tid + j * 576;
        if (li < 1536) {
            const int row = li >> 3, pl = (li >> 2) & 1, qt = li & 3;
            const unsigned* src = pl ? Glo : Ghi;
            st[j] = *(const u32x4*)(src + row * 192 + koff + qt * 4);
        }
    }
}
__device__ __forceinline__ void fw_stage_write(unsigned* sb, int tid, const u32x4 st[3]) {
    #pragma unroll
    for (int j = 0; j < 3; ++j) {
        const int li = tid + j * 576;
        if (li < 1536) {
            const int row = li >> 3, pl = (li >> 2) & 1, qt = li & 3;
            *(u32x4*)(sb + pl * 3840 + row * 20 + qt * 4) = st[j];
        }
    }
}

__global__ __launch_bounds__(576) void fwdq_k(
    const float* __restrict__ traj,
    const unsigned* __restrict__ Ghi, const unsigned* __restrict__ Glo,
    float* __restrict__ wre, float* __restrict__ wim,
    const int mode,
    float* __restrict__ qre, float* __restrict__ qim)
{
    __shared__ unsigned sG[2][2 * 3840];   // 60 KB
    const int tid = threadIdx.x;
    const int lane = tid & 63, wid = tid >> 6;         // wid 0..8
    const int l15 = lane & 15, q = lane >> 4;
    const int m = (blockIdx.x * 9 + wid) * 16 + l15;
    const float2 kk = *(const float2*)(traj + 2 * m);
    float kxh, kxl, kyh, kyl;
    ksplit(kk.x, kxh, kxl);
    ksplit(kk.y, kyh, kyl);

    f32x4 tre[12], tim[12];
    #pragma unroll
    for (int i = 0; i < 12; ++i) {
        tre[i] = (f32x4){0.f, 0.f, 0.f, 0.f};
        tim[i] = (f32x4){0.f, 0.f, 0.f, 0.f};
    }

    float bc, bs;
    { const float ph = redphase(kyh, kyl, (float)(q * 4 - 96)); 
      bc = __builtin_amdgcn_cosf(ph); bs = __builtin_amdgcn_sinf(ph); }
    const float r1c = __builtin_amdgcn_cosf(kk.y), r1s = __builtin_amdgcn_sinf(kk.y);
    float r16c, r16s;
    { float g = kk.y * 16.f; g -= rintf(g);
      r16c = __builtin_amdgcn_cosf(g); r16s = __builtin_amdgcn_sinf(g); }

    u32x4 st[3];
    fw_stage_load(Ghi, Glo, tid, 0, st);
    fw_stage_write(&sG[0][0], tid, st);
    __syncthreads();

    for (int ch = 0; ch < 12; ++ch) {
        if (ch < 11) fw_stage_load(Ghi, Glo, tid, (ch + 1) * 16, st);

        u32x4 Ph, Pl, Qh, Ql;
        {
            float c = bc, s = bs;
            #pragma unroll
            for (int r = 0; r < 4; ++r) {
                unsigned h, l; split_pk(c, s, h, l);
                Ph[r] = h; Pl[r] = l;
                Qh[r] = rot16(h) ^ 0x00008000u;
                Ql[r] = rot16(l) ^ 0x00008000u;
                const float nc = c * r1c - s * r1s, ns = s * r1c + c * r1s;
                c = nc; s = ns;
            }
            const float nbc = bc * r16c - bs * r16s, nbs = bs * r16c + bc * r16s;
            bc = nbc; bs = nbs;
        }

        const unsigned* sb = &sG[ch & 1][0];
        #pragma unroll
        for (int si = 0; si < 12; ++si) {
            const int base = (si * 16 + l15) * 20 + q * 4;
            const u32x4 gh = *(const u32x4*)(sb + base);
            const u32x4 gl = *(const u32x4*)(sb + 3840 + base);
            tre[si] = mfma_bf16(gh, Ph, tre[si]);
            tre[si] = mfma_bf16(gh, Pl, tre[si]);
            tre[si] = mfma_bf16(gl, Ph, tre[si]);
            tim[si] = mfma_bf16(gh, Qh, tim[si]);
            tim[si] = mfma_bf16(gh, Ql, tim[si]);
            tim[si] = mfma_bf16(gl, Qh, tim[si]);
        }

        if (ch < 11) {
            // write targets buf[(ch+1)&1]; every wave in iter ch reads only
            // buf[ch&1]; stragglers in iter ch-1 are impossible past the
            // previous barrier -> no WAR. Single RAW barrier after the write.
            fw_stage_write(&sG[(ch + 1) & 1][0], tid, st);
            __syncthreads();
        }
    }

    float qr = 0.f, qi = 0.f;
    {
        float g = kk.x * 16.f; g -= rintf(g);
        const float rc = __builtin_amdgcn_cosf(g), rs = __builtin_amdgcn_sinf(g);
        #pragma unroll
        for (int rg = 0; rg < 4; ++rg) {
            const float ph = redphase(kxh, kxl, (float)(q * 4 + rg - 96));
            float c = __builtin_amdgcn_cosf(ph), s = __builtin_amdgcn_sinf(ph);
            #pragma unroll
            for (int si = 0; si < 12; ++si) {
                const float tr = tre[si][rg], ti = tim[si][rg];
                qr += c * tr + s * ti;
                qi += c * ti - s * tr;
                const float nc = c * rc - s * rs, ns = s * rc + c * rs;
                c = nc; s = ns;
            }
        }
    }
    qr += __shfl_xor(qr, 16); qi += __shfl_xor(qi, 16);
    qr += __shfl_xor(qr, 32); qi += __shfl_xor(qi, 32);
    if (lane < 16) {
        if (mode == 0) {
            const float den = fmaxf(sqrtf(qr * qr + qi * qi), 1e-20f);
            wre[m] /= den; wim[m] /= den;
        } else {
            const float sc = sqrtf(wre[m] * wre[m] + wim[m] * wim[m]);
            qre[m] = qr * sc; qim[m] = qi * sc;
        }
    }
}

// ---------------------------------------------------------------------------
__global__ void presplit_k(const float* __restrict__ re, const float* __restrict__ im,
                           unsigned* __restrict__ Gh, unsigned* __restrict__ Gl) {
    const int e = blockIdx.x * 256 + threadIdx.x;
    unsigned h, l;
    split_pk(re[e], im[e], h, l);     // low16 = re (even K), high16 = im (odd K)
    Gh[e] = h; Gl[e] = l;
}

// Reduce PG partial images + presplit (pipe path)
__global__ void presplitP_k(const float* __restrict__ outP,
                            unsigned* __restrict__ Gh, unsigned* __restrict__ Gl) {
    const int e = blockIdx.x * 256 + threadIdx.x;
    float re = 0.f, im = 0.f;
    #pragma unroll 8
    for (int g = 0; g < PG; ++g) {
        re += outP[(size_t)g * (2 * MTOT) + e];
        im += outP[(size_t)g * (2 * MTOT) + MTOT + e];
    }
    unsigned h, l;
    split_pk(re, im, h, l);
    Gh[e] = h; Gl[e] = l;
}

// Reduce PG partial images -> final output
__global__ void reduceOut_k(const float* __restrict__ outP, float* __restrict__ out) {
    const int e = blockIdx.x * 256 + threadIdx.x;
    float re = 0.f, im = 0.f;
    #pragma unroll 8
    for (int g = 0; g < PG; ++g) {
        re += outP[(size_t)g * (2 * MTOT) + e];
        im += outP[(size_t)g * (2 * MTOT) + MTOT + e];
    }
    out[e] = re; out[MTOT + e] = im;
}

// ---------------------------------------------------------------------------
extern "C" void kernel_launch(void* const* d_in, const int* in_sizes, int n_in,
                              void* d_out, int out_size, void* d_ws, size_t ws_size,
                              hipStream_t stream)
{
    const float* xin  = (const float*)d_in[0];   // (2,192,192)
    const float* traj = (const float*)d_in[1];   // (36864,2)
    float* out = (float*)d_out;                  // (2,192,192)

    char* pb = (char*)d_ws;
    unsigned* BS = (unsigned*)pb; pb += (size_t)2304 * 6144 * 4;   // 56.6 MB
    float* outP = (float*)pb; pb += (size_t)PG * 2 * MTOT * 4;     // 18.9 MB
    float* wr   = (float*)pb; pb += MTOT * 4;
    float* wi   = (float*)pb; pb += MTOT * 4;
    float* dre  = (float*)pb; pb += MTOT * 4;
    float* dim_ = (float*)pb; pb += MTOT * 4;
    unsigned* Ghi = (unsigned*)pb; pb += MTOT * 4;
    unsigned* Glo = (unsigned*)pb; pb += MTOT * 4;

    precompP_k<<<dim3(MTOT / 256, NPIX), 256, 0, stream>>>(traj, 1, BS);
    winit_k<<<MTOT / 256, 256, 0, stream>>>(wr, wi);

    for (int it = 0; it < 3; ++it) {
        adj_gemm_k<<<9 * GRP, 256, 0, stream>>>(traj, wr, wi, BS, outP);
        presplitP_k<<<MTOT / 256, 256, 0, stream>>>(outP, Ghi, Glo);
        fwdq_k<<<256, 576, 0, stream>>>(traj, Ghi, Glo, wr, wi, 0, dre, dim_);
    }

    presplit_k<<<MTOT / 256, 256, 0, stream>>>(xin, xin + MTOT, Ghi, Glo);
    fwdq_k<<<256, 576, 0, stream>>>(traj, Ghi, Glo, wr, wi, 1, dre, dim_);
    adj_gemm_k<<<9 * GRP, 256, 0, stream>>>(traj, dre, dim_, BS, outP);
    reduceOut_k<<<MTOT / 256, 256, 0, stream>>>(outP, out);
}